// Round 1
// 391.217 us; speedup vs baseline: 1.0041x; 1.0041x over previous
//
#include <hip/hip_runtime.h>
#include <math.h>

#define H 256
#define W 256
#define NB 8
#define CIN 64
#define COUT 128
#define HW (H * W)

typedef float f4v __attribute__((ext_vector_type(4)));

// ---------------------------------------------------------------------------
// Kernel A (fused): offset conv (k=0..2, all 64 ci) + tanh + cumsum -> ynew.
// Wave-private tiles: each wave stages its own 10x40 halo tile per channel
// (double-buffered), 2-deep register prefetch, NO __syncthreads anywhere.
// Tile reads are b128 (bank-group spread (2a+q)%8 -> conflict-free) except
// the two edge elements (b0.w / b2.x) which the compiler narrows to b32.
// Epilogue: t_k = tanh(acc_k); y0=t0+t1, y1=t1, y2=t1+t2 written directly.
// ---------------------------------------------------------------------------
__global__ __launch_bounds__(256) void koffset2(const float* __restrict__ x,
                                                const float* __restrict__ offw,
                                                float* __restrict__ ynew) {
    __shared__ float tile[4][2][10 * 40];  // [wave][buf][10 rows x 40 cols]
    const int n = blockIdx.z;
    const int i0 = blockIdx.y * 32;
    const int j0 = blockIdx.x * 32;
    const int tid = threadIdx.x;
    const int wv = tid >> 6;
    const int lane = tid & 63;
    const int rloc = lane >> 3;        // 0..7: output row within wave
    const int lj4 = (lane & 7) << 2;   // output col quad
    const int iw0 = i0 + 8 * wv - 1;   // global row of tile row 0

    // staging slot 1: slots 0..63 (slot s -> row s/10, col-block s%10)
    const int a1 = lane / 10, q1 = lane - a1 * 10;
    const int gi1 = iw0 + a1, gj1 = j0 - 4 + 4 * q1;
    const bool v1 = ((unsigned)gi1 < (unsigned)H) && ((unsigned)gj1 < (unsigned)W);
    const size_t off1 = v1 ? ((size_t)gi1 * W + gj1) : 0;

    // staging slot 2: slots 64..99 (lanes 0..35 only)
    const int s2 = lane + 64;
    const int a2 = s2 / 10, q2 = s2 - a2 * 10;
    const int gi2 = iw0 + a2, gj2 = j0 - 4 + 4 * q2;
    const bool hv2 = (s2 < 100);
    const bool v2 = hv2 && ((unsigned)gi2 < (unsigned)H) && ((unsigned)gj2 < (unsigned)W);
    const size_t off2 = v2 ? ((size_t)gi2 * W + gj2) : 0;

    const float* xn = x + (size_t)n * CIN * HW;
    const float4 zf4 = make_float4(0.f, 0.f, 0.f, 0.f);

    // 2-deep prefetch: ra = data(c), rb = data(c+1) at loop top
    float4 ra1 = v1 ? *(const float4*)(xn + off1) : zf4;
    float4 ra2 = v2 ? *(const float4*)(xn + off2) : zf4;
    float4 rb1 = v1 ? *(const float4*)(xn + HW + off1) : zf4;
    float4 rb2 = v2 ? *(const float4*)(xn + HW + off2) : zf4;
    const float* p1 = xn + 2 * HW + off1;
    const float* p2 = xn + 2 * HW + off2;

    float acc[3][4];
#pragma unroll
    for (int k = 0; k < 3; ++k)
#pragma unroll
        for (int d = 0; d < 4; ++d) acc[k][d] = 0.f;

    float* buf0 = &tile[wv][0][0];
    float* buf1 = &tile[wv][1][0];

    for (int c = 0; c < CIN; c += 2) {
#pragma unroll
        for (int h = 0; h < 2; ++h) {
            float* buf = h ? buf1 : buf0;
            // stage data(c+h) into this wave's buffer (linear b128 writes)
            *(float4*)(buf + 4 * lane) = ra1;
            if (hv2) *(float4*)(buf + 4 * s2) = ra2;
            // rotate prefetch pipeline, issue load for c+h+2
            ra1 = rb1;
            ra2 = rb2;
            if (c + h + 2 < CIN) {
                rb1 = v1 ? *(const float4*)p1 : zf4;
                rb2 = v2 ? *(const float4*)p2 : zf4;
                p1 += HW;
                p2 += HW;
            }
            // compute 3x3 conv contributions for this channel
            const float* wp = offw + (size_t)(c + h) * 9;  // offw[k][ci][u][v], k stride 576
#pragma unroll
            for (int u = 0; u < 3; ++u) {
                const float* rp = buf + (rloc + u) * 40 + lj4;
                float4 b0 = *(const float4*)(rp);
                float4 b1 = *(const float4*)(rp + 4);
                float4 b2 = *(const float4*)(rp + 8);
                const float r0 = b0.w, r1 = b1.x, r2 = b1.y, r3 = b1.z, r4 = b1.w, r5 = b2.x;
#pragma unroll
                for (int k = 0; k < 3; ++k) {
                    const float w0 = wp[k * 576 + u * 3 + 0];
                    const float w1 = wp[k * 576 + u * 3 + 1];
                    const float w2 = wp[k * 576 + u * 3 + 2];
                    acc[k][0] += r0 * w0 + r1 * w1 + r2 * w2;
                    acc[k][1] += r1 * w0 + r2 * w1 + r3 * w2;
                    acc[k][2] += r2 * w0 + r3 * w1 + r4 * w2;
                    acc[k][3] += r3 * w0 + r4 * w1 + r5 * w2;
                }
            }
        }
    }

    // epilogue: tanh + cumsum combos, write ynew directly
    float y[3][4];
#pragma unroll
    for (int d = 0; d < 4; ++d) {
        float t0 = tanhf(acc[0][d]);
        float t1 = tanhf(acc[1][d]);
        float t2 = tanhf(acc[2][d]);
        y[0][d] = t0 + t1;
        y[1][d] = t1;
        y[2][d] = t1 + t2;
    }
    size_t base = (size_t)n * 3 * HW + (size_t)(i0 + 8 * wv + rloc) * W + (j0 + lj4);
#pragma unroll
    for (int k = 0; k < 3; ++k)
        *(float4*)(ynew + base + (size_t)k * HW) =
            make_float4(y[k][0], y[k][1], y[k][2], y[k][3]);
}

// ---------------------------------------------------------------------------
// Kernel B: P[n][co][t] (padded stride 16), t = r*4+y.   (unchanged, verified)
// ---------------------------------------------------------------------------
__global__ __launch_bounds__(256) void kpmat(const float* __restrict__ x,
                                             const float* __restrict__ convw,
                                             float* __restrict__ P) {
    __shared__ float xl[CIN * 4];
    __shared__ float wl[16 * 192];
    const int n = blockIdx.x >> 3;
    const int co0 = (blockIdx.x & 7) * 16;
    const int tid = threadIdx.x;
    {
        int ci = tid >> 2, y = tid & 3;
        xl[tid] = x[(((size_t)n * CIN + ci) * H + y) * W];
    }
    for (int p = tid; p < 16 * 192; p += 256) wl[p] = convw[co0 * 192 + p];
    __syncthreads();
    if (tid < 192) {
        int co = tid / 12, t = tid - co * 12;
        int r = t >> 2, y = t & 3;
        float s = 0.f;
#pragma unroll
        for (int ci = 0; ci < CIN; ++ci) s += wl[co * 192 + ci * 3 + r] * xl[ci * 4 + y];
        P[((size_t)n * COUT + co0 + co) * 16 + t] = s;
    }
}

// ---------------------------------------------------------------------------
// Kernel C: out[n,co,i,j] = sum_t C[t](n,i,j) * P[n,co,t]  (unchanged, verified)
// ---------------------------------------------------------------------------
__global__ __launch_bounds__(256) void kout(const float* __restrict__ ynew,
                                            const float* __restrict__ P,
                                            float* __restrict__ out) {
    __shared__ float Cs[12 * 256];
    __shared__ float Pl[128 * 16];
    const int n = blockIdx.y;
    const int i = blockIdx.x;
    const int tid = threadIdx.x;

    {
        const f4v* src = (const f4v*)(P + (size_t)n * COUT * 16);
        f4v* dst = (f4v*)Pl;
        dst[tid] = src[tid];
        dst[tid + 256] = src[tid + 256];
    }

    {
        const int j = tid;
        float c[12];
#pragma unroll
        for (int t = 0; t < 12; ++t) c[t] = 0.f;
#pragma unroll
        for (int r = 0; r < 3; ++r) {
            int rowi = 3 * i + r;
            int k = rowi >> 8;
            int i2 = rowi & 255;
            float g = (float)(((k + i2 + j) % 3) - 1) +
                      ynew[((size_t)n * 3 + k) * (H * W) + i2 * W + j];
            float gy = g / 127.5f - 1.0f;
            float iy = ((gy + 1.0f) * 256.0f - 1.0f) * 0.5f;
            float fy = floorf(iy);
            int y0 = (int)fy;
            float w1 = iy - fy;
            if ((unsigned)y0 < 4u) c[r * 4 + y0] += 0.5f * (1.0f - w1);
            int y1 = y0 + 1;
            if ((unsigned)y1 < 4u) c[r * 4 + y1] += 0.5f * w1;
        }
#pragma unroll
        for (int t = 0; t < 12; ++t) Cs[t * 256 + j] = c[t];
    }
    __syncthreads();

    const int jq = (tid & 63) * 4;
    const int cg = tid >> 6;
    float4 cc[12];
#pragma unroll
    for (int t = 0; t < 12; ++t) cc[t] = *(const float4*)&Cs[t * 256 + jq];

    float* op = out + (((size_t)n * COUT) * H + i) * W;
    for (int co = cg * 32; co < cg * 32 + 32; ++co) {
        const float4* pp = (const float4*)&Pl[co * 16];
        float4 P0 = pp[0], P1 = pp[1], P2 = pp[2];
        float pv[12] = {P0.x, P0.y, P0.z, P0.w, P1.x, P1.y, P1.z, P1.w,
                        P2.x, P2.y, P2.z, P2.w};
        f4v a = {0.f, 0.f, 0.f, 0.f};
#pragma unroll
        for (int t = 0; t < 12; ++t) {
            a.x += pv[t] * cc[t].x;
            a.y += pv[t] * cc[t].y;
            a.z += pv[t] * cc[t].z;
            a.w += pv[t] * cc[t].w;
        }
        __builtin_nontemporal_store(a, (f4v*)(op + (size_t)co * (H * W) + jq));
    }
}

// ---------------------------------------------------------------------------
extern "C" void kernel_launch(void* const* d_in, const int* in_sizes, int n_in,
                              void* d_out, int out_size, void* d_ws, size_t ws_size,
                              hipStream_t stream) {
    const float* x = (const float*)d_in[0];      // [8,64,256,256]
    const float* offw = (const float*)d_in[1];   // [6,64,3,3]
    const float* convw = (const float*)d_in[2];  // [128,64,3,1]
    float* out = (float*)d_out;                  // [8,128,256,256]

    float* ynew = (float*)d_ws;                           // [8][3][256][256]
    float* P = ynew + (size_t)NB * 3 * HW;                // [8][128][16]

    koffset2<<<dim3(8, 8, NB), 256, 0, stream>>>(x, offw, ynew);
    kpmat<<<dim3(64), 256, 0, stream>>>(x, convw, P);
    kout<<<dim3(H, NB), 256, 0, stream>>>(ynew, P, out);
}